// Round 4
// baseline (762.150 us; speedup 1.0000x reference)
//
#include <hip/hip_runtime.h>
#include <stdint.h>

// Problem shape (fixed by the reference): M = B*S = 8192, K = DIN = 4096, N = DOUT = 4096
#define MDIM 8192
#define KDIM 4096
#define NDIM 4096

typedef float f32x4 __attribute__((ext_vector_type(4)));
typedef __bf16 bf16x8 __attribute__((ext_vector_type(8)));
typedef short short8 __attribute__((ext_vector_type(8)));
typedef float fl4 __attribute__((ext_vector_type(4)));
typedef int i32x4 __attribute__((ext_vector_type(4)));

// fp32 -> bf16 bits, round-to-nearest-even (values here are small integers: exact <= 256)
__device__ __forceinline__ short f2bf_bits(float f) {
    unsigned int u = __float_as_uint(f);
    u += 0x7fffu + ((u >> 16) & 1u);
    return (short)(u >> 16);
}

// 8 fp32 activations -> 8 bf16 bits of rintf(x * inv_is)  (integer-valued, exact <= 256)
__device__ __forceinline__ short8 cvt_x8(fl4 a, fl4 b, float inv_is) {
    short8 o;
    o[0] = f2bf_bits(rintf(a[0] * inv_is));
    o[1] = f2bf_bits(rintf(a[1] * inv_is));
    o[2] = f2bf_bits(rintf(a[2] * inv_is));
    o[3] = f2bf_bits(rintf(a[3] * inv_is));
    o[4] = f2bf_bits(rintf(b[0] * inv_is));
    o[5] = f2bf_bits(rintf(b[1] * inv_is));
    o[6] = f2bf_bits(rintf(b[2] * inv_is));
    o[7] = f2bf_bits(rintf(b[3] * inv_is));
    return o;
}

// 8 int32 weights -> 8 bf16 bits (|w| <= 127: exact)
__device__ __forceinline__ short8 cvt_w8(i32x4 a, i32x4 b) {
    short8 o;
    o[0] = f2bf_bits((float)a[0]);
    o[1] = f2bf_bits((float)a[1]);
    o[2] = f2bf_bits((float)a[2]);
    o[3] = f2bf_bits((float)a[3]);
    o[4] = f2bf_bits((float)b[0]);
    o[5] = f2bf_bits((float)b[1]);
    o[6] = f2bf_bits((float)b[2]);
    o[7] = f2bf_bits((float)b[3]);
    return o;
}

// R4: FULLY FUSED quant + NT GEMM + requant. No workspace, no quant kernels.
// C[m,n] = round((is*ws[n]*sum_k rint(x[m,k]/is)*w[n,k] + bias[n]) / os)
//
// Staging: register-prefetch (tile k+1 issued before MFMA of tile k) -> convert fp32/int32
// to bf16 in VGPRs -> ds_write_b128 into XOR-swizzled LDS (conflicts = 0, verified R2).
// Unlike global_load_lds, plain register loads need no vmcnt(0) drain at the barrier, so
// the prefetch stays in flight across it (AITER-style). Saves the 301 MB quant-pass
// round trip (~207 us at this container's ~1.5 TB/s streaming ceiling).
// Block mapping: plain bid order (R3's supertile remap regressed: real concurrency is
// ~640 blocks, for which the natural 20x32 span is already near-optimal).
__global__ void __launch_bounds__(256) gemm_fused_kernel(
    const float* __restrict__ x,     // [MDIM][KDIM] fp32
    const int* __restrict__ w,       // [NDIM][KDIM] int32 (int8-valued)
    const int* __restrict__ bias,    // [NDIM]
    const float* __restrict__ wscale,// [NDIM]
    const float* __restrict__ p_is,
    const float* __restrict__ p_os,
    int* __restrict__ out) {         // [MDIM][NDIM] int32
    __shared__ __align__(16) short As[128 * 32];
    __shared__ __align__(16) short Bs[128 * 32];

    const int tid  = threadIdx.x;
    const int lane = tid & 63;
    const int wave = tid >> 6;
    const int quad = lane >> 4;
    const int r16  = lane & 15;
    const int rsw  = (r16 >> 1) & 3;   // read-side swizzle selector

    const int n0 = blockIdx.x * 128;
    const int m0 = blockIdx.y * 128;

    const int wm = (wave & 1) * 64;
    const int wn = (wave >> 1) * 64;

    const float inv_is = 1.0f / p_is[0];

    // staging geometry: thread handles chunk (tid&3) [8 elems] of rows srow and srow+64
    const int srow   = tid >> 2;                 // 0..63
    const int chunk  = tid & 3;
    const int pchunk = chunk ^ ((srow >> 1) & 3); // XOR swizzle (same phase for srow+64)

    const float* gA  = x + (int64_t)(m0 + srow) * KDIM + chunk * 8;
    const float* gA2 = gA + (int64_t)64 * KDIM;
    const int*   gB  = w + (int64_t)(n0 + srow) * KDIM + chunk * 8;
    const int*   gB2 = gB + (int64_t)64 * KDIM;

    short* wA0 = As + srow * 32 + pchunk * 8;
    short* wA1 = As + (srow + 64) * 32 + pchunk * 8;
    short* wB0 = Bs + srow * 32 + pchunk * 8;
    short* wB1 = Bs + (srow + 64) * 32 + pchunk * 8;

    f32x4 acc[4][4];
#pragma unroll
    for (int i = 0; i < 4; ++i)
#pragma unroll
        for (int j = 0; j < 4; ++j) acc[i][j] = (f32x4)0.0f;

    // register prefetch buffers (tile k in flight)
    fl4   ar0, ar1, ar2, ar3;
    i32x4 br0, br1, br2, br3;
#define LOAD_TILE(k)                                    \
    do {                                                \
        ar0 = *(const fl4*)(gA + (k));                  \
        ar1 = *(const fl4*)(gA + (k) + 4);              \
        ar2 = *(const fl4*)(gA2 + (k));                 \
        ar3 = *(const fl4*)(gA2 + (k) + 4);             \
        br0 = *(const i32x4*)(gB + (k));                \
        br1 = *(const i32x4*)(gB + (k) + 4);            \
        br2 = *(const i32x4*)(gB2 + (k));               \
        br3 = *(const i32x4*)(gB2 + (k) + 4);           \
    } while (0)

    LOAD_TILE(0);

    for (int k0 = 0; k0 < KDIM; k0 += 32) {
        // convert tile k (vmcnt wait lands here, after prev iter's MFMA)
        short8 sa0 = cvt_x8(ar0, ar1, inv_is);
        short8 sa1 = cvt_x8(ar2, ar3, inv_is);
        short8 sb0 = cvt_w8(br0, br1);
        short8 sb1 = cvt_w8(br2, br3);

        __syncthreads();               // prev tile's ds_reads done before overwrite
        *(short8*)wA0 = sa0;
        *(short8*)wA1 = sa1;
        *(short8*)wB0 = sb0;
        *(short8*)wB1 = sb1;

        // issue next tile's global loads BEFORE the barrier + MFMA (stay in flight across both)
        if (k0 + 32 < KDIM) LOAD_TILE(k0 + 32);

        __syncthreads();               // LDS writes visible

        bf16x8 af[4], bfr[4];
#pragma unroll
        for (int mi = 0; mi < 4; ++mi)
            af[mi] = *(const bf16x8*)(As + (wm + mi * 16 + r16) * 32 + (quad ^ rsw) * 8);
#pragma unroll
        for (int ni = 0; ni < 4; ++ni)
            bfr[ni] = *(const bf16x8*)(Bs + (wn + ni * 16 + r16) * 32 + (quad ^ rsw) * 8);

#pragma unroll
        for (int mi = 0; mi < 4; ++mi)
#pragma unroll
            for (int ni = 0; ni < 4; ++ni)
                acc[mi][ni] = __builtin_amdgcn_mfma_f32_16x16x32_bf16(
                    af[mi], bfr[ni], acc[mi][ni], 0, 0, 0);
    }
#undef LOAD_TILE

    // epilogue: out = round((is*ws[n]*acc + bias[n]) / os)
    const float is = p_is[0];
    const float inv_os = 1.0f / p_os[0];

    float alpha[4], beta[4];
#pragma unroll
    for (int ni = 0; ni < 4; ++ni) {
        const int col = n0 + wn + ni * 16 + r16;
        alpha[ni] = is * wscale[col] * inv_os;
        beta[ni]  = (float)bias[col] * inv_os;
    }

    // C/D layout (verified m89/m91): col = lane&15, row = quad*4 + reg
#pragma unroll
    for (int mi = 0; mi < 4; ++mi) {
        const int row0 = m0 + wm + mi * 16 + quad * 4;
#pragma unroll
        for (int ni = 0; ni < 4; ++ni) {
            const int col = n0 + wn + ni * 16 + r16;
#pragma unroll
            for (int reg = 0; reg < 4; ++reg) {
                const float v = acc[mi][ni][reg] * alpha[ni] + beta[ni];
                out[(int64_t)(row0 + reg) * NDIM + col] = __float2int_rn(v);
            }
        }
    }
}

extern "C" void kernel_launch(void* const* d_in, const int* in_sizes, int n_in,
                              void* d_out, int out_size, void* d_ws, size_t ws_size,
                              hipStream_t stream) {
    (void)in_sizes; (void)n_in; (void)out_size; (void)d_ws; (void)ws_size;
    const float* x      = (const float*)d_in[0];
    const int*   weight = (const int*)d_in[1];
    const int*   bias   = (const int*)d_in[2];
    const float* wscale = (const float*)d_in[3];
    const float* p_is   = (const float*)d_in[4];
    const float* p_os   = (const float*)d_in[5];

    dim3 grid(NDIM / 128, MDIM / 128);
    gemm_fused_kernel<<<grid, 256, 0, stream>>>(x, weight, bias, wscale, p_is, p_os,
                                                (int*)d_out);
}